// Round 16
// baseline (1335.914 us; speedup 1.0000x reference)
//
#include <hip/hip_runtime.h>
#include <hip/hip_bf16.h>

typedef unsigned short u16;
typedef unsigned int u32;
typedef float f32x4 __attribute__((ext_vector_type(4)));
typedef __bf16 bf16x8 __attribute__((ext_vector_type(8)));

#define NB 2
#define NT 1024
#define ND 1024
#define NH 16
#define HDIM 64
#define NL 6
#define NV 32000
#define ND4 4096
#define BT (NB * NT)
#define L2E 1.44269504f
#define NSLOT 500  // logits loss-partial slots per row: 125 ntiles * 4 waves

__device__ __forceinline__ u16 f2b(float f) {
  u32 u = __builtin_bit_cast(u32, f);
  u32 r = (u + 0x7FFFu + ((u >> 16) & 1u)) >> 16;
  return (u16)r;
}

__device__ __forceinline__ void gl_lds16(const void* g, void* lds) {
  __builtin_amdgcn_global_load_lds((const __attribute__((address_space(1))) u32*)g,
                                   (__attribute__((address_space(3))) u32*)lds, 16, 0, 0);
}

__device__ __forceinline__ float rsum16(float v) {
  v += __shfl_xor(v, 1, 64);
  v += __shfl_xor(v, 2, 64);
  v += __shfl_xor(v, 4, 64);
  v += __shfl_xor(v, 8, 64);
  return v;
}

// --------------------------------------------- f32 [K][N] -> bf16 [N][K] (512 thr)
__device__ __forceinline__ void tr512(const float* in, int in_rs, u16* out, int out_rs,
                                      int k0, int n0, float (*t)[65]) {
  int tid = threadIdx.x;
#pragma unroll
  for (int i = 0; i < 8; ++i) {
    int e = tid + 512 * i;
    int r = e >> 6, c = e & 63;
    t[r][c] = in[(size_t)(k0 + r) * in_rs + n0 + c];
  }
  __syncthreads();
#pragma unroll
  for (int i = 0; i < 8; ++i) {
    int e = tid + 512 * i;
    int r = e >> 6, c = e & 63;
    out[(size_t)(n0 + r) * out_rs + k0 + c] = f2b(t[c][r]);
  }
}

// One 64x64 tile of the per-layer weight transposes (512-thread blocks).
__device__ __forceinline__ void trans512_blk(
    int i, int l, const float* Wq, const float* Wk, const float* Wv,
    const float* Wo, const float* W1, const float* W2,
    u16* wqkvT, u16* woT, u16* w1T, u16* w2T, float (*t)[65]) {
  if (i < 768) {  // qkv: [L][H][D][HD] -> [3D][D]
    int x = i & 15, z = i >> 4;
    int s = z >> 4, h = z & 15;
    const float* in = (s == 0 ? Wq : s == 1 ? Wk : Wv) + ((size_t)(l * NH + h)) * ND * HDIM;
    u16* o = wqkvT + ((size_t)(s * ND + h * HDIM)) * ND;
    tr512(in, HDIM, o, ND, x * 64, 0, t);
  } else if (i < 1024) {  // Wo
    int j = i - 768, x = j & 15, y = j >> 4;
    tr512(Wo + (size_t)l * ND * ND, ND, woT, ND, y * 64, x * 64, t);
  } else if (i < 2048) {  // W1
    int j = i - 1024, x = j & 63, y = j >> 6;
    tr512(W1 + (size_t)l * ND * ND4, ND4, w1T, ND, y * 64, x * 64, t);
  } else {  // W2
    int j = i - 2048, x = j & 15, y = j >> 4;
    tr512(W2 + (size_t)l * ND4 * ND, ND, w2T, ND4, y * 64, x * 64, t);
  }
}

// ---------------------------------------------------------------- pre: embed + trans(l=0)
__global__ void __launch_bounds__(512) k_pre(const int* __restrict__ idx,
                                             const float* __restrict__ tok,
                                             const float* __restrict__ pos,
                                             float* __restrict__ xf, u16* __restrict__ xb,
                                             const float* __restrict__ Wq,
                                             const float* __restrict__ Wk,
                                             const float* __restrict__ Wv,
                                             const float* __restrict__ Wo,
                                             const float* __restrict__ W1,
                                             const float* __restrict__ W2,
                                             u16* __restrict__ wT0) {
  __shared__ float t[64][65];
  int bid = blockIdx.x;
  if (bid < 1024) {  // embedding: 2 rows per block
    int tid = threadIdx.x;
    int row = bid * 2 + (tid >> 8);
    int tt = row & (NT - 1);
    int tk = idx[row];
    int c = (tid & 255) * 4;
    float4 a = *(const float4*)(tok + (size_t)tk * ND + c);
    float4 p = *(const float4*)(pos + (size_t)tt * ND + c);
    float4 s = make_float4(a.x + p.x, a.y + p.y, a.z + p.z, a.w + p.w);
    *(float4*)(xf + (size_t)row * ND + c) = s;
    u16* o = xb + (size_t)row * ND + c;
    *(u32*)(o + 0) = (u32)f2b(s.x) | ((u32)f2b(s.y) << 16);
    *(u32*)(o + 2) = (u32)f2b(s.z) | ((u32)f2b(s.w) << 16);
    return;
  }
  trans512_blk(bid - 1024, 0, Wq, Wk, Wv, Wo, W1, W2,
               wT0, wT0 + (size_t)3 * ND * ND, wT0 + (size_t)4 * ND * ND,
               wT0 + (size_t)8 * ND * ND, t);
}

// ---------------------------------------------------------------- GEMM 256x256, BK=64
// m201-style 8-phase schedule (R12 ledger — best measured). 0 bank conflicts.
template <int EPI>
__global__ void __launch_bounds__(512, 2)
k_gemm8(const u16* __restrict__ A, const u16* __restrict__ Bt,
        const float* __restrict__ bias, float* __restrict__ outf,
        u16* __restrict__ outb, int K, int N, int nMt, float* __restrict__ pl) {
  __shared__ u16 lds[2][2][2][128 * 64];
  int tid = threadIdx.x;
  int w = tid >> 6, l = tid & 63;
  int l4 = l >> 4, lm = l & 15;
  int wm = w >> 2, wn = w & 3;

  int nwg = gridDim.x, bid = blockIdx.x;
  int q8 = nwg >> 3, r8 = nwg & 7;
  int xcd = bid & 7, loc = bid >> 3;
  int swz = (xcd < r8 ? xcd * (q8 + 1) : r8 * (q8 + 1) + (xcd - r8) * q8) + loc;
  int m0 = (swz % nMt) * 256;
  int n0 = (swz / nMt) * 256;

  f32x4 acc[8][4];
  f32x4 z = {0.f, 0.f, 0.f, 0.f};
#pragma unroll
  for (int m = 0; m < 8; ++m)
#pragma unroll
    for (int n = 0; n < 4; ++n) acc[m][n] = z;

  int srow = (w << 3) + (l >> 3);
  int scol = (((l & 7) ^ ((l >> 3) & 7)) << 3);
  int sdst = w * 512 + l * 8;

  auto stage_half = [&](int b, int mat, int h, int kt) {
    int k0 = kt << 6;
    const u16* base = (mat == 0 ? A + (size_t)(m0 + (h << 7)) * K
                                : Bt + (size_t)(n0 + (h << 7)) * K);
#pragma unroll
    for (int i = 0; i < 2; ++i)
      gl_lds16(base + (size_t)(i * 64 + srow) * K + k0 + scol,
               &lds[b][mat][h][i * 4096 + sdst]);
  };

  int c0 = (l4 ^ (lm & 7)) * 8;
  int c1 = c0 ^ 32;
  int brow0 = (wn & 1) * 64;

  const u16* A0h = &lds[0][0][wm][0];
  const u16* B0h = &lds[0][1][wn >> 1][0];
  const u16* A1h = &lds[1][0][wm][0];
  const u16* B1h = &lds[1][1][wn >> 1][0];

  bf16x8 Ar[4][2], Bx[2][2], By[2][2];

  auto dsA = [&](const u16* Ah, int mf0) {
#pragma unroll
    for (int mf = 0; mf < 4; ++mf) {
      Ar[mf][0] = *(const bf16x8*)&Ah[((mf0 + mf) * 16 + lm) * 64 + c0];
      Ar[mf][1] = *(const bf16x8*)&Ah[((mf0 + mf) * 16 + lm) * 64 + c1];
    }
  };
  auto dsB = [&](const u16* Bh, bf16x8 (&B)[2][2], int nf0) {
#pragma unroll
    for (int nf = 0; nf < 2; ++nf) {
      B[nf][0] = *(const bf16x8*)&Bh[(brow0 + (nf0 + nf) * 16 + lm) * 64 + c0];
      B[nf][1] = *(const bf16x8*)&Bh[(brow0 + (nf0 + nf) * 16 + lm) * 64 + c1];
    }
  };
  auto mm = [&](int am, bf16x8 (&B)[2][2], int an) {
    __builtin_amdgcn_s_setprio(1);
#pragma unroll
    for (int mf = 0; mf < 4; ++mf)
#pragma unroll
      for (int nf = 0; nf < 2; ++nf) {
        acc[am + mf][an + nf] =
            __builtin_amdgcn_mfma_f32_16x16x32_bf16(Ar[mf][0], B[nf][0], acc[am + mf][an + nf], 0, 0, 0);
        acc[am + mf][an + nf] =
            __builtin_amdgcn_mfma_f32_16x16x32_bf16(Ar[mf][1], B[nf][1], acc[am + mf][an + nf], 0, 0, 0);
      }
    __builtin_amdgcn_s_setprio(0);
  };
  auto openbar = [&]() {
    __builtin_amdgcn_sched_barrier(0);
    __builtin_amdgcn_s_barrier();
    __builtin_amdgcn_sched_barrier(0);
  };
  auto midbar = [&]() {
    __builtin_amdgcn_sched_barrier(0);
    __builtin_amdgcn_s_barrier();
    asm volatile("s_waitcnt lgkmcnt(0)" ::: "memory");
    __builtin_amdgcn_sched_barrier(0);
  };

  int nk = K >> 6;
  stage_half(0, 0, 0, 0); stage_half(0, 0, 1, 0);
  stage_half(0, 1, 0, 0); stage_half(0, 1, 1, 0);
  stage_half(1, 0, 0, 1);

  for (int u = 0; u < nk; u += 2) {
    bool s2 = (u + 2 < nk), s3 = (u + 3 < nk);
    asm volatile("s_waitcnt vmcnt(2)" ::: "memory");
    openbar();
    dsA(A0h, 0); dsB(B0h, Bx, 0);
    stage_half(1, 0, 1, u + 1);
    midbar();
    mm(0, Bx, 0);
    openbar();
    dsB(B0h, By, 2);
    stage_half(1, 1, 0, u + 1);
    midbar();
    mm(0, By, 2);
    openbar();
    dsA(A0h, 4);
    stage_half(1, 1, 1, u + 1);
    midbar();
    mm(4, By, 2);
    openbar();
    if (s2) stage_half(0, 0, 0, u + 2);
    midbar();
    mm(4, Bx, 0);
    if (s2) asm volatile("s_waitcnt vmcnt(2)" ::: "memory");
    else    asm volatile("s_waitcnt vmcnt(0)" ::: "memory");
    openbar();
    dsA(A1h, 0); dsB(B1h, Bx, 0);
    if (s2) stage_half(0, 0, 1, u + 2);
    midbar();
    mm(0, Bx, 0);
    openbar();
    dsB(B1h, By, 2);
    if (s2) stage_half(0, 1, 0, u + 2);
    midbar();
    mm(0, By, 2);
    openbar();
    dsA(A1h, 4);
    if (s2) stage_half(0, 1, 1, u + 2);
    midbar();
    mm(4, By, 2);
    openbar();
    if (s3) stage_half(1, 0, 0, u + 3);
    midbar();
    mm(4, Bx, 0);
  }

  if constexpr (EPI == 4) {
    int slot = (n0 >> 6) + wn;
#pragma unroll
    for (int mf = 0; mf < 8; ++mf)
#pragma unroll
      for (int j = 0; j < 4; ++j) {
        int row = m0 + wm * 128 + mf * 16 + l4 * 4 + j;
        float sm = 0.f;
#pragma unroll
        for (int nf = 0; nf < 4; ++nf) {
          int col = n0 + wn * 64 + nf * 16 + lm;
          float v = acc[mf][nf][j] + bias[col];
          __builtin_nontemporal_store(v, &outf[(size_t)row * N + col]);
          sm += exp2f(v * L2E);
        }
        sm = rsum16(sm);
        if (lm == 0) pl[(size_t)row * NSLOT + slot] = sm;
      }
  } else {
#pragma unroll
    for (int mf = 0; mf < 8; ++mf)
#pragma unroll
      for (int nf = 0; nf < 4; ++nf)
#pragma unroll
        for (int j = 0; j < 4; ++j) {
          int row = m0 + wm * 128 + mf * 16 + l4 * 4 + j;
          int col = n0 + wn * 64 + nf * 16 + lm;
          float v = acc[mf][nf][j];
          if constexpr (EPI == 0) outb[(size_t)row * N + col] = f2b(v);
          else __builtin_nontemporal_store(v + bias[col], &outf[(size_t)row * N + col]);
        }
  }
}

// ---------------------------------------------------------------- GEMM BMxBN, BK=64
// R5-proven loop. EPI 5: bf16 store + V-columns (col>=2048) scatter to vT[bh][e][t]
// (16B-contiguous-in-keys layout for barrier-free attention PV reads).
template <int EPI, int BM, int BN>
__global__ void __launch_bounds__(256, BM == 64 ? 4 : (BN == 64 ? 3 : 2))
k_gemm4(const u16* __restrict__ A, const u16* __restrict__ Bt,
        const float* __restrict__ bias, float* __restrict__ outf,
        u16* __restrict__ outb, int K, int N, int nMt, u16* __restrict__ vt) {
  constexpr int NFW = BN / 32;
  constexpr int NH2 = NFW / 2;
  constexpr int AF = BM / 32;       // A frags per wave
  __shared__ u16 As[2][BM * 64];
  __shared__ u16 Bs[2][BN * 64];
  int tid = threadIdx.x;
  int w = tid >> 6, l = tid & 63;
  int l4 = l >> 4, lm = l & 15;
  int wr = w >> 1, wc = w & 1;

  int nwg = gridDim.x, bid = blockIdx.x;
  int q8 = nwg >> 3, r8 = nwg & 7;
  int xcd = bid & 7, loc = bid >> 3;
  int swz = (xcd < r8 ? xcd * (q8 + 1) : r8 * (q8 + 1) + (xcd - r8) * q8) + loc;
  int m0 = (swz % nMt) * BM;
  int n0 = (swz / nMt) * BN;

  f32x4 acc[AF][NFW];
  f32x4 z = {0.f, 0.f, 0.f, 0.f};
#pragma unroll
  for (int m = 0; m < AF; ++m)
#pragma unroll
    for (int n = 0; n < NFW; ++n) acc[m][n] = z;

  int srow = (w << 3) + (l >> 3);
  int scol = (((l & 7) ^ ((l >> 3) & 7)) << 3);
  int sdst = w * 512 + l * 8;

  const u16* Arow = A + (size_t)m0 * K;
  const u16* Brow = Bt + (size_t)n0 * K;

  auto stage = [&](int b, int kt) {
    int k0 = kt << 6;
#pragma unroll
    for (int i = 0; i < BM / 32; ++i)
      gl_lds16(Arow + (size_t)(i * 32 + srow) * K + k0 + scol, &As[b][i * 2048 + sdst]);
#pragma unroll
    for (int i = 0; i < BN / 32; ++i)
      gl_lds16(Brow + (size_t)(i * 32 + srow) * K + k0 + scol, &Bs[b][i * 2048 + sdst]);
  };

  int c0 = (l4 ^ (lm & 7)) * 8;
  int c1 = c0 ^ 32;

  int nk = K >> 6;
  stage(0, 0);
  for (int t = 0; t < nk; ++t) {
    int b = t & 1;
    asm volatile("s_waitcnt vmcnt(0)" ::: "memory");
    __builtin_amdgcn_sched_barrier(0);
    __builtin_amdgcn_s_barrier();
    __builtin_amdgcn_sched_barrier(0);
    if (t + 1 < nk) stage(b ^ 1, t + 1);
    __builtin_amdgcn_sched_barrier(0);

    bf16x8 af[AF][2], bfr[NH2][2];
#pragma unroll
    for (int mf = 0; mf < AF; ++mf) {
      af[mf][0] = *(const bf16x8*)&As[b][(mf * 16 + lm) * 64 + c0 + wr * (BM / 2) * 64];
      af[mf][1] = *(const bf16x8*)&As[b][(mf * 16 + lm) * 64 + c1 + wr * (BM / 2) * 64];
    }
#pragma unroll
    for (int nf = 0; nf < NH2; ++nf) {
      int brow = wc * (BN / 2) + nf * 16 + lm;
      bfr[nf][0] = *(const bf16x8*)&Bs[b][brow * 64 + c0];
      bfr[nf][1] = *(const bf16x8*)&Bs[b][brow * 64 + c1];
    }
    __builtin_amdgcn_s_setprio(1);
#pragma unroll
    for (int mf = 0; mf < AF; ++mf)
#pragma unroll
      for (int nf = 0; nf < NH2; ++nf) {
        acc[mf][nf] = __builtin_amdgcn_mfma_f32_16x16x32_bf16(af[mf][0], bfr[nf][0], acc[mf][nf], 0, 0, 0);
        acc[mf][nf] = __builtin_amdgcn_mfma_f32_16x16x32_bf16(af[mf][1], bfr[nf][1], acc[mf][nf], 0, 0, 0);
      }
    __builtin_amdgcn_s_setprio(0);

#pragma unroll
    for (int nf = 0; nf < NH2; ++nf) {
      int brow = wc * (BN / 2) + (nf + NH2) * 16 + lm;
      bfr[nf][0] = *(const bf16x8*)&Bs[b][brow * 64 + c0];
      bfr[nf][1] = *(const bf16x8*)&Bs[b][brow * 64 + c1];
    }
    __builtin_amdgcn_s_setprio(1);
#pragma unroll
    for (int mf = 0; mf < AF; ++mf)
#pragma unroll
      for (int nf = 0; nf < NH2; ++nf) {
        acc[mf][nf + NH2] = __builtin_amdgcn_mfma_f32_16x16x32_bf16(af[mf][0], bfr[nf][0], acc[mf][nf + NH2], 0, 0, 0);
        acc[mf][nf + NH2] = __builtin_amdgcn_mfma_f32_16x16x32_bf16(af[mf][1], bfr[nf][1], acc[mf][nf + NH2], 0, 0, 0);
      }
    __builtin_amdgcn_s_setprio(0);
  }

#pragma unroll
  for (int mf = 0; mf < AF; ++mf)
#pragma unroll
    for (int nf = 0; nf < NFW; ++nf)
#pragma unroll
      for (int j = 0; j < 4; ++j) {
        int row = m0 + wr * (BM / 2) + mf * 16 + l4 * 4 + j;
        int col = n0 + wc * (BN / 2) + nf * 16 + lm;
        float v = acc[mf][nf][j];
        if constexpr (EPI == 0 || EPI == 5) {
          u16 bv = f2b(v);
          outb[(size_t)row * N + col] = bv;
          if constexpr (EPI == 5) {
            if (col >= 2048)  // V: vT[(b*1024 + col-2048)][token]
              vt[((size_t)((row >> 10) * 1024 + col - 2048) << 10) | (row & 1023)] = bv;
          }
        } else if constexpr (EPI == 2) {
          v += bias[col];
          outb[(size_t)row * N + col] = f2b(fmaxf(v, 0.f));
        } else {
          v += bias[col];
          size_t o = (size_t)row * N + col;
          float nx = outf[o] + v;
          outf[o] = nx;
          outb[o] = f2b(nx);
        }
      }
}

// ---------------------------------------------------------------- attn + trans backfill
// blocks 0..255: attn(l), ONE q-tile per block. NO K/V LDS staging: K fragments
// read directly from qkv (L2-resident), V fragments from vT[bh][e][t] (both 16B
// contiguous). KV loop is BARRIER-FREE (Pw is wave-private; lgkmcnt only).
// Max-free softmax; ONE rsum16 after the loop. LDS = Pw only (35 KB) -> 2 blk/CU.
// blocks 256..: next-layer weight transposes + Wf chunk.
__global__ void __launch_bounds__(512, 2) k_attn_mega(
    const u16* __restrict__ qkv, const u16* __restrict__ vT, u16* __restrict__ ob,
    const float* __restrict__ Wq, const float* __restrict__ Wk,
    const float* __restrict__ Wv, const float* __restrict__ Wo,
    const float* __restrict__ W1, const float* __restrict__ W2,
    const float* __restrict__ Wf, u16* __restrict__ wTnext,
    u16* __restrict__ wfT, int lNext, int wfStart) {
  __shared__ char smem[34816];
  int bid = blockIdx.x;
  if (bid >= 256) {
    auto t = reinterpret_cast<float(*)[65]>(smem);
    int i = bid - 256;
    int nTrans = (lNext < NL) ? 3072 : 0;
    if (i < nTrans) {
      trans512_blk(i, lNext, Wq, Wk, Wv, Wo, W1, W2,
                   wTnext, wTnext + (size_t)3 * ND * ND, wTnext + (size_t)4 * ND * ND,
                   wTnext + (size_t)8 * ND * ND, t);
    } else {
      int j = wfStart + (i - nTrans);  // Wf tile index [0, 8000)
      int x = j % 500, y = j / 500;
      tr512(Wf, NV, wfT, ND, y * 64, x * 64, t);
    }
    return;
  }
  // ---------------- attn: one q-tile, barrier-free ----------------
  u16* Pw = (u16*)smem;          // [8][16][136]
  int qb = bid & 7, h = (bid >> 3) & 15, b = bid >> 7;
  int tid = threadIdx.x;
  int w = tid >> 6, l = tid & 63;
  int l4 = l >> 4, lm = l & 15;

  const u16* base = qkv + (size_t)b * NT * 3072 + h * HDIM;
  const u16* vbase = vT + ((size_t)(b * NH + h) << 16);  // [64][1024] u16

  f32x4 z = {0.f, 0.f, 0.f, 0.f};

  bf16x8 qf[2];
#pragma unroll
  for (int kk = 0; kk < 2; ++kk) {
    int tq = qb * 128 + w * 16 + lm;
    qf[kk] = *(const bf16x8*)(base + (size_t)tq * 3072 + kk * 32 + l4 * 8);
  }

  f32x4 oacc[4];
  float lrow[4];
#pragma unroll
  for (int n = 0; n < 4; ++n) oacc[n] = z;
#pragma unroll
  for (int j = 0; j < 4; ++j) lrow[j] = 0.f;

  for (int kb = 0; kb <= qb; ++kb) {
    // S = Q K^T : K fragments straight from global (L2)
    f32x4 s[8];
#pragma unroll
    for (int n = 0; n < 8; ++n) s[n] = z;
#pragma unroll
    for (int kk = 0; kk < 2; ++kk)
#pragma unroll
      for (int n = 0; n < 8; ++n) {
        bf16x8 kf = *(const bf16x8*)(base + (size_t)(kb * 128 + n * 16 + lm) * 3072 +
                                     1024 + kk * 32 + l4 * 8);
        s[n] = __builtin_amdgcn_mfma_f32_16x16x32_bf16(qf[kk], kf, s[n], 0, 0, 0);
      }

    bool diag = (kb == qb);
#pragma unroll
    for (int j = 0; j < 4; ++j) {
      int rloc = w * 16 + l4 * 4 + j;
      int prow = l4 * 4 + j;
      float rs = 0.f;
#pragma unroll
      for (int n = 0; n < 8; ++n) {
        float p = exp2f(s[n][j] * (0.03125f * L2E));
        if (diag && (n * 16 + lm > rloc)) p = 0.f;
        rs += p;
        Pw[(w * 16 + prow) * 136 + n * 16 + lm] = f2b(p);
      }
      lrow[j] += rs;
    }
    asm volatile("s_waitcnt lgkmcnt(0)" ::: "memory");  // Pw cross-lane (intra-wave)
    __builtin_amdgcn_sched_barrier(0);

    // O += P V : V fragments from vT (8 contiguous keys per 16B load)
#pragma unroll
    for (int kk = 0; kk < 4; ++kk) {
      bf16x8 pa = *(const bf16x8*)&Pw[(w * 16 + lm) * 136 + kk * 32 + l4 * 8];
#pragma unroll
      for (int n = 0; n < 4; ++n) {
        bf16x8 vf = *(const bf16x8*)(vbase + ((size_t)(n * 16 + lm) << 10) +
                                     kb * 128 + kk * 32 + l4 * 8);
        oacc[n] = __builtin_amdgcn_mfma_f32_16x16x32_bf16(pa, vf, oacc[n], 0, 0, 0);
      }
    }
    __builtin_amdgcn_sched_barrier(0);  // keep Pw reads before next-iter overwrites
  }

#pragma unroll
  for (int j = 0; j < 4; ++j) lrow[j] = rsum16(lrow[j]);

#pragma unroll
  for (int n = 0; n < 4; ++n)
#pragma unroll
    for (int j = 0; j < 4; ++j) {
      int tq = qb * 128 + w * 16 + l4 * 4 + j;
      int col = h * HDIM + n * 16 + lm;
      float v = oacc[n][j] / lrow[j];
      ob[(size_t)(b * NT + tq) * ND + col] = f2b(v);
    }
}

// ---------------------------------------------------------------- layernorm
__global__ void k_ln(const float* __restrict__ xf, const float* __restrict__ g,
                     const float* __restrict__ bta, u16* __restrict__ xb) {
  __shared__ float red[4];
  int row = blockIdx.x, tid = threadIdx.x;
  int w = tid >> 6;
  int c = tid * 4;
  float4 x = *(const float4*)(xf + (size_t)row * ND + c);
  float s = x.x + x.y + x.z + x.w;
#pragma unroll
  for (int off = 1; off < 64; off <<= 1) s += __shfl_xor(s, off, 64);
  if ((tid & 63) == 0) red[w] = s;
  __syncthreads();
  float mu = (red[0] + red[1] + red[2] + red[3]) * (1.0f / ND);
  float d0 = x.x - mu, d1 = x.y - mu, d2 = x.z - mu, d3 = x.w - mu;
  float v = d0 * d0 + d1 * d1 + d2 * d2 + d3 * d3;
  __syncthreads();
#pragma unroll
  for (int off = 1; off < 64; off <<= 1) v += __shfl_xor(v, off, 64);
  if ((tid & 63) == 0) red[w] = v;
  __syncthreads();
  float var = (red[0] + red[1] + red[2] + red[3]) * (1.0f / ND);
  float rs = rsqrtf(var + 1e-5f);
  float4 gg = *(const float4*)(g + c);
  float4 bb = *(const float4*)(bta + c);
  u16* o = xb + (size_t)row * ND + c;
  o[0] = f2b(d0 * rs * gg.x + bb.x);
  o[1] = f2b(d1 * rs * gg.y + bb.y);
  o[2] = f2b(d2 * rs * gg.z + bb.z);
  o[3] = f2b(d3 * rs * gg.w + bb.w);
}

// ---------------------------------------------------------------- loss (from partials)
__global__ void k_loss_row2(const float* __restrict__ pl, const float* __restrict__ logits,
                            const int* __restrict__ tgt, float* __restrict__ lossbuf) {
  int row = blockIdx.x, l = threadIdx.x;  // 64 threads
  const float* pr = pl + (size_t)row * NSLOT;
  float s = 0.f;
  for (int i = l; i < NSLOT; i += 64) s += pr[i];
#pragma unroll
  for (int off = 1; off < 64; off <<= 1) s += __shfl_xor(s, off, 64);
  if (l == 0) lossbuf[row] = logf(s) - logits[(size_t)row * NV + tgt[row]];
}

__global__ void k_loss_final(const float* __restrict__ lossbuf, float* __restrict__ out) {
  __shared__ float red[4];
  int tid = threadIdx.x;
  float s = 0.f;
  for (int i = tid; i < BT; i += 256) s += lossbuf[i];
#pragma unroll
  for (int off = 1; off < 64; off <<= 1) s += __shfl_xor(s, off, 64);
  if ((tid & 63) == 0) red[tid >> 6] = s;
  __syncthreads();
  if (tid == 0) out[0] = (red[0] + red[1] + red[2] + red[3]) * (1.0f / BT);
}

// ---------------------------------------------------------------- launch
extern "C" void kernel_launch(void* const* d_in, const int* in_sizes, int n_in,
                              void* d_out, int out_size, void* d_ws, size_t ws_size,
                              hipStream_t stream) {
  const int* idx = (const int*)d_in[0];
  const int* tgt = (const int*)d_in[1];
  const float* tok = (const float*)d_in[2];
  const float* pos = (const float*)d_in[3];
  const float* Wq = (const float*)d_in[4];
  const float* Wk = (const float*)d_in[5];
  const float* Wv = (const float*)d_in[6];
  const float* Wo = (const float*)d_in[7];
  const float* bo = (const float*)d_in[8];
  const float* W1 = (const float*)d_in[9];
  const float* b1 = (const float*)d_in[10];
  const float* W2 = (const float*)d_in[11];
  const float* b2 = (const float*)d_in[12];
  const float* lng = (const float*)d_in[13];
  const float* lnb = (const float*)d_in[14];
  const float* Wf = (const float*)d_in[15];
  const float* bfp = (const float*)d_in[16];
  float* logits = (float*)d_out;
  float* lossp = logits + (size_t)BT * NV;

  char* ws = (char*)d_ws;
  u16* wT0 = (u16*)ws;                                   // 12*D^2 u16 = 25.2 MB
  u16* wT1 = wT0 + (size_t)12 * ND * ND;                 // 25.2 MB
  u16* wfT = wT1 + (size_t)12 * ND * ND;                 // 65.5 MB
  size_t off = (size_t)24 * ND * ND * 2 + (size_t)NV * ND * 2;
  float* xf = (float*)(ws + off); off += (size_t)BT * ND * 4;
  u16* xb = (u16*)(ws + off);     off += (size_t)BT * ND * 2;
  u16* qkv = (u16*)(ws + off);    off += (size_t)BT * 3 * ND * 2;
  u16* vTb = (u16*)(ws + off);    off += (size_t)NB * NH * HDIM * NT * 2;  // 4 MB
  u16* obuf = (u16*)(ws + off);   off += (size_t)BT * ND * 2;
  u16* hb = (u16*)(ws + off);     off += (size_t)BT * ND4 * 2;
  float* pl = (float*)(ws + off); off += (size_t)BT * NSLOT * 4;
  float* lossbuf = (float*)(ws + off);

  k_pre<<<4096, 512, 0, stream>>>(idx, tok, pos, xf, xb, Wq, Wk, Wv, Wo, W1, W2, wT0);
  int wfDone = 0;
  for (int l = 0; l < NL; ++l) {
    u16* wTl = (l & 1) ? wT1 : wT0;
    u16* wTn = (l & 1) ? wT0 : wT1;
    u16* wqkvT = wTl;
    u16* woT = wTl + (size_t)3 * ND * ND;
    u16* w1T = wTl + (size_t)4 * ND * ND;
    u16* w2T = wTl + (size_t)8 * ND * ND;
    k_gemm4<5, 128, 128><<<384, 256, 0, stream>>>(xb, wqkvT, nullptr, nullptr, qkv, ND, 3 * ND, 16, vTb);
    int nTrans = (l + 1 < NL) ? 3072 : 0;
    int wfCount = (l + 1 < NL) ? 1333 : (8000 - wfDone);
    k_attn_mega<<<256 + nTrans + wfCount, 512, 0, stream>>>(
        qkv, vTb, obuf, Wq, Wk, Wv, Wo, W1, W2, Wf, wTn, wfT, l + 1, wfDone);
    wfDone += wfCount;
    k_gemm4<3, 64, 64><<<512, 256, 0, stream>>>(obuf, woT, bo + (size_t)l * ND, xf, xb, ND, ND, 32, nullptr);
    k_gemm4<2, 128, 128><<<512, 256, 0, stream>>>(xb, w1T, b1 + (size_t)l * ND4, nullptr, hb, ND, ND4, 16, nullptr);
    k_gemm4<3, 64, 64><<<512, 256, 0, stream>>>(hb, w2T, b2 + (size_t)l * ND, xf, xb, ND4, ND, 32, nullptr);
  }
  k_ln<<<BT, 256, 0, stream>>>(xf, lng, lnb, xb);
  k_gemm8<4><<<1000, 512, 0, stream>>>(xb, wfT, bfp, logits, nullptr, ND, NV, 8, pl);
  k_loss_row2<<<BT, 64, 0, stream>>>(pl, logits, tgt, lossbuf);
  k_loss_final<<<1, 256, 0, stream>>>(lossbuf, lossp);
}

// Round 17
// 1068.689 us; speedup vs baseline: 1.2500x; 1.2500x over previous
//
#include <hip/hip_runtime.h>
#include <hip/hip_bf16.h>

typedef unsigned short u16;
typedef unsigned int u32;
typedef float f32x4 __attribute__((ext_vector_type(4)));
typedef __bf16 bf16x8 __attribute__((ext_vector_type(8)));

#define NB 2
#define NT 1024
#define ND 1024
#define NH 16
#define HDIM 64
#define NL 6
#define NV 32000
#define ND4 4096
#define BT (NB * NT)
#define L2E 1.44269504f
#define NSLOT 500  // logits loss-partial slots per row: 125 ntiles * 4 waves

__device__ __forceinline__ u16 f2b(float f) {
  u32 u = __builtin_bit_cast(u32, f);
  u32 r = (u + 0x7FFFu + ((u >> 16) & 1u)) >> 16;
  return (u16)r;
}

__device__ __forceinline__ void gl_lds16(const void* g, void* lds) {
  __builtin_amdgcn_global_load_lds((const __attribute__((address_space(1))) u32*)g,
                                   (__attribute__((address_space(3))) u32*)lds, 16, 0, 0);
}

__device__ __forceinline__ float rsum16(float v) {
  v += __shfl_xor(v, 1, 64);
  v += __shfl_xor(v, 2, 64);
  v += __shfl_xor(v, 4, 64);
  v += __shfl_xor(v, 8, 64);
  return v;
}

// --------------------------------------------- f32 [K][N] -> bf16 [N][K] (512 thr)
__device__ __forceinline__ void tr512(const float* in, int in_rs, u16* out, int out_rs,
                                      int k0, int n0, float (*t)[65]) {
  int tid = threadIdx.x;
#pragma unroll
  for (int i = 0; i < 8; ++i) {
    int e = tid + 512 * i;
    int r = e >> 6, c = e & 63;
    t[r][c] = in[(size_t)(k0 + r) * in_rs + n0 + c];
  }
  __syncthreads();
#pragma unroll
  for (int i = 0; i < 8; ++i) {
    int e = tid + 512 * i;
    int r = e >> 6, c = e & 63;
    out[(size_t)(n0 + r) * out_rs + k0 + c] = f2b(t[c][r]);
  }
}

// One 64x64 tile of the per-layer weight transposes (512-thread blocks).
__device__ __forceinline__ void trans512_blk(
    int i, int l, const float* Wq, const float* Wk, const float* Wv,
    const float* Wo, const float* W1, const float* W2,
    u16* wqkvT, u16* woT, u16* w1T, u16* w2T, float (*t)[65]) {
  if (i < 768) {  // qkv: [L][H][D][HD] -> [3D][D]
    int x = i & 15, z = i >> 4;
    int s = z >> 4, h = z & 15;
    const float* in = (s == 0 ? Wq : s == 1 ? Wk : Wv) + ((size_t)(l * NH + h)) * ND * HDIM;
    u16* o = wqkvT + ((size_t)(s * ND + h * HDIM)) * ND;
    tr512(in, HDIM, o, ND, x * 64, 0, t);
  } else if (i < 1024) {  // Wo
    int j = i - 768, x = j & 15, y = j >> 4;
    tr512(Wo + (size_t)l * ND * ND, ND, woT, ND, y * 64, x * 64, t);
  } else if (i < 2048) {  // W1
    int j = i - 1024, x = j & 63, y = j >> 6;
    tr512(W1 + (size_t)l * ND * ND4, ND4, w1T, ND, y * 64, x * 64, t);
  } else {  // W2
    int j = i - 2048, x = j & 15, y = j >> 4;
    tr512(W2 + (size_t)l * ND4 * ND, ND, w2T, ND4, y * 64, x * 64, t);
  }
}

// ---------------------------------------------------------------- pre: embed + trans(l=0)
__global__ void __launch_bounds__(512) k_pre(const int* __restrict__ idx,
                                             const float* __restrict__ tok,
                                             const float* __restrict__ pos,
                                             float* __restrict__ xf, u16* __restrict__ xb,
                                             const float* __restrict__ Wq,
                                             const float* __restrict__ Wk,
                                             const float* __restrict__ Wv,
                                             const float* __restrict__ Wo,
                                             const float* __restrict__ W1,
                                             const float* __restrict__ W2,
                                             u16* __restrict__ wT0) {
  __shared__ float t[64][65];
  int bid = blockIdx.x;
  if (bid < 1024) {  // embedding: 2 rows per block
    int tid = threadIdx.x;
    int row = bid * 2 + (tid >> 8);
    int tt = row & (NT - 1);
    int tk = idx[row];
    int c = (tid & 255) * 4;
    float4 a = *(const float4*)(tok + (size_t)tk * ND + c);
    float4 p = *(const float4*)(pos + (size_t)tt * ND + c);
    float4 s = make_float4(a.x + p.x, a.y + p.y, a.z + p.z, a.w + p.w);
    *(float4*)(xf + (size_t)row * ND + c) = s;
    u16* o = xb + (size_t)row * ND + c;
    *(u32*)(o + 0) = (u32)f2b(s.x) | ((u32)f2b(s.y) << 16);
    *(u32*)(o + 2) = (u32)f2b(s.z) | ((u32)f2b(s.w) << 16);
    return;
  }
  trans512_blk(bid - 1024, 0, Wq, Wk, Wv, Wo, W1, W2,
               wT0, wT0 + (size_t)3 * ND * ND, wT0 + (size_t)4 * ND * ND,
               wT0 + (size_t)8 * ND * ND, t);
}

// ---------------------------------------------------------------- GEMM 256x256, BK=64
// m201-style 8-phase schedule (R12 ledger — best measured). 0 bank conflicts.
template <int EPI>
__global__ void __launch_bounds__(512, 2)
k_gemm8(const u16* __restrict__ A, const u16* __restrict__ Bt,
        const float* __restrict__ bias, float* __restrict__ outf,
        u16* __restrict__ outb, int K, int N, int nMt, float* __restrict__ pl) {
  __shared__ u16 lds[2][2][2][128 * 64];
  int tid = threadIdx.x;
  int w = tid >> 6, l = tid & 63;
  int l4 = l >> 4, lm = l & 15;
  int wm = w >> 2, wn = w & 3;

  int nwg = gridDim.x, bid = blockIdx.x;
  int q8 = nwg >> 3, r8 = nwg & 7;
  int xcd = bid & 7, loc = bid >> 3;
  int swz = (xcd < r8 ? xcd * (q8 + 1) : r8 * (q8 + 1) + (xcd - r8) * q8) + loc;
  int m0 = (swz % nMt) * 256;
  int n0 = (swz / nMt) * 256;

  f32x4 acc[8][4];
  f32x4 z = {0.f, 0.f, 0.f, 0.f};
#pragma unroll
  for (int m = 0; m < 8; ++m)
#pragma unroll
    for (int n = 0; n < 4; ++n) acc[m][n] = z;

  int srow = (w << 3) + (l >> 3);
  int scol = (((l & 7) ^ ((l >> 3) & 7)) << 3);
  int sdst = w * 512 + l * 8;

  auto stage_half = [&](int b, int mat, int h, int kt) {
    int k0 = kt << 6;
    const u16* base = (mat == 0 ? A + (size_t)(m0 + (h << 7)) * K
                                : Bt + (size_t)(n0 + (h << 7)) * K);
#pragma unroll
    for (int i = 0; i < 2; ++i)
      gl_lds16(base + (size_t)(i * 64 + srow) * K + k0 + scol,
               &lds[b][mat][h][i * 4096 + sdst]);
  };

  int c0 = (l4 ^ (lm & 7)) * 8;
  int c1 = c0 ^ 32;
  int brow0 = (wn & 1) * 64;

  const u16* A0h = &lds[0][0][wm][0];
  const u16* B0h = &lds[0][1][wn >> 1][0];
  const u16* A1h = &lds[1][0][wm][0];
  const u16* B1h = &lds[1][1][wn >> 1][0];

  bf16x8 Ar[4][2], Bx[2][2], By[2][2];

  auto dsA = [&](const u16* Ah, int mf0) {
#pragma unroll
    for (int mf = 0; mf < 4; ++mf) {
      Ar[mf][0] = *(const bf16x8*)&Ah[((mf0 + mf) * 16 + lm) * 64 + c0];
      Ar[mf][1] = *(const bf16x8*)&Ah[((mf0 + mf) * 16 + lm) * 64 + c1];
    }
  };
  auto dsB = [&](const u16* Bh, bf16x8 (&B)[2][2], int nf0) {
#pragma unroll
    for (int nf = 0; nf < 2; ++nf) {
      B[nf][0] = *(const bf16x8*)&Bh[(brow0 + (nf0 + nf) * 16 + lm) * 64 + c0];
      B[nf][1] = *(const bf16x8*)&Bh[(brow0 + (nf0 + nf) * 16 + lm) * 64 + c1];
    }
  };
  auto mm = [&](int am, bf16x8 (&B)[2][2], int an) {
    __builtin_amdgcn_s_setprio(1);
#pragma unroll
    for (int mf = 0; mf < 4; ++mf)
#pragma unroll
      for (int nf = 0; nf < 2; ++nf) {
        acc[am + mf][an + nf] =
            __builtin_amdgcn_mfma_f32_16x16x32_bf16(Ar[mf][0], B[nf][0], acc[am + mf][an + nf], 0, 0, 0);
        acc[am + mf][an + nf] =
            __builtin_amdgcn_mfma_f32_16x16x32_bf16(Ar[mf][1], B[nf][1], acc[am + mf][an + nf], 0, 0, 0);
      }
    __builtin_amdgcn_s_setprio(0);
  };
  auto openbar = [&]() {
    __builtin_amdgcn_sched_barrier(0);
    __builtin_amdgcn_s_barrier();
    __builtin_amdgcn_sched_barrier(0);
  };
  auto midbar = [&]() {
    __builtin_amdgcn_sched_barrier(0);
    __builtin_amdgcn_s_barrier();
    asm volatile("s_waitcnt lgkmcnt(0)" ::: "memory");
    __builtin_amdgcn_sched_barrier(0);
  };

  int nk = K >> 6;
  stage_half(0, 0, 0, 0); stage_half(0, 0, 1, 0);
  stage_half(0, 1, 0, 0); stage_half(0, 1, 1, 0);
  stage_half(1, 0, 0, 1);

  for (int u = 0; u < nk; u += 2) {
    bool s2 = (u + 2 < nk), s3 = (u + 3 < nk);
    asm volatile("s_waitcnt vmcnt(2)" ::: "memory");
    openbar();
    dsA(A0h, 0); dsB(B0h, Bx, 0);
    stage_half(1, 0, 1, u + 1);
    midbar();
    mm(0, Bx, 0);
    openbar();
    dsB(B0h, By, 2);
    stage_half(1, 1, 0, u + 1);
    midbar();
    mm(0, By, 2);
    openbar();
    dsA(A0h, 4);
    stage_half(1, 1, 1, u + 1);
    midbar();
    mm(4, By, 2);
    openbar();
    if (s2) stage_half(0, 0, 0, u + 2);
    midbar();
    mm(4, Bx, 0);
    if (s2) asm volatile("s_waitcnt vmcnt(2)" ::: "memory");
    else    asm volatile("s_waitcnt vmcnt(0)" ::: "memory");
    openbar();
    dsA(A1h, 0); dsB(B1h, Bx, 0);
    if (s2) stage_half(0, 0, 1, u + 2);
    midbar();
    mm(0, Bx, 0);
    openbar();
    dsB(B1h, By, 2);
    if (s2) stage_half(0, 1, 0, u + 2);
    midbar();
    mm(0, By, 2);
    openbar();
    dsA(A1h, 4);
    if (s2) stage_half(0, 1, 1, u + 2);
    midbar();
    mm(4, By, 2);
    openbar();
    if (s3) stage_half(1, 0, 0, u + 3);
    midbar();
    mm(4, Bx, 0);
  }

  if constexpr (EPI == 4) {
    int slot = (n0 >> 6) + wn;
#pragma unroll
    for (int mf = 0; mf < 8; ++mf)
#pragma unroll
      for (int j = 0; j < 4; ++j) {
        int row = m0 + wm * 128 + mf * 16 + l4 * 4 + j;
        float sm = 0.f;
#pragma unroll
        for (int nf = 0; nf < 4; ++nf) {
          int col = n0 + wn * 64 + nf * 16 + lm;
          float v = acc[mf][nf][j] + bias[col];
          __builtin_nontemporal_store(v, &outf[(size_t)row * N + col]);
          sm += exp2f(v * L2E);
        }
        sm = rsum16(sm);
        if (lm == 0) pl[(size_t)row * NSLOT + slot] = sm;
      }
  } else {
#pragma unroll
    for (int mf = 0; mf < 8; ++mf)
#pragma unroll
      for (int nf = 0; nf < 4; ++nf)
#pragma unroll
        for (int j = 0; j < 4; ++j) {
          int row = m0 + wm * 128 + mf * 16 + l4 * 4 + j;
          int col = n0 + wn * 64 + nf * 16 + lm;
          float v = acc[mf][nf][j];
          if constexpr (EPI == 0) outb[(size_t)row * N + col] = f2b(v);
          else __builtin_nontemporal_store(v + bias[col], &outf[(size_t)row * N + col]);
        }
  }
}

// ---------------------------------------------------------------- GEMM BMxBN, BK=64
// R5-proven loop: 2 LDS buffers, ONE barrier/KT (vmcnt(0) drain), stage(next)
// issued right after the barrier; XOR swizzle (0 conflicts).
// (128,128): 64 KiB -> 2 blk/CU. (64,64): 32 KiB -> 4 blk/CU.
template <int EPI, int BM, int BN>
__global__ void __launch_bounds__(256, BM == 64 ? 4 : (BN == 64 ? 3 : 2))
k_gemm4(const u16* __restrict__ A, const u16* __restrict__ Bt,
        const float* __restrict__ bias, float* __restrict__ outf,
        u16* __restrict__ outb, int K, int N, int nMt) {
  constexpr int NFW = BN / 32;
  constexpr int NH2 = NFW / 2;
  constexpr int AF = BM / 32;       // A frags per wave
  __shared__ u16 As[2][BM * 64];
  __shared__ u16 Bs[2][BN * 64];
  int tid = threadIdx.x;
  int w = tid >> 6, l = tid & 63;
  int l4 = l >> 4, lm = l & 15;
  int wr = w >> 1, wc = w & 1;

  int nwg = gridDim.x, bid = blockIdx.x;
  int q8 = nwg >> 3, r8 = nwg & 7;
  int xcd = bid & 7, loc = bid >> 3;
  int swz = (xcd < r8 ? xcd * (q8 + 1) : r8 * (q8 + 1) + (xcd - r8) * q8) + loc;
  int m0 = (swz % nMt) * BM;
  int n0 = (swz / nMt) * BN;

  f32x4 acc[AF][NFW];
  f32x4 z = {0.f, 0.f, 0.f, 0.f};
#pragma unroll
  for (int m = 0; m < AF; ++m)
#pragma unroll
    for (int n = 0; n < NFW; ++n) acc[m][n] = z;

  int srow = (w << 3) + (l >> 3);
  int scol = (((l & 7) ^ ((l >> 3) & 7)) << 3);
  int sdst = w * 512 + l * 8;

  const u16* Arow = A + (size_t)m0 * K;
  const u16* Brow = Bt + (size_t)n0 * K;

  auto stage = [&](int b, int kt) {
    int k0 = kt << 6;
#pragma unroll
    for (int i = 0; i < BM / 32; ++i)
      gl_lds16(Arow + (size_t)(i * 32 + srow) * K + k0 + scol, &As[b][i * 2048 + sdst]);
#pragma unroll
    for (int i = 0; i < BN / 32; ++i)
      gl_lds16(Brow + (size_t)(i * 32 + srow) * K + k0 + scol, &Bs[b][i * 2048 + sdst]);
  };

  int c0 = (l4 ^ (lm & 7)) * 8;
  int c1 = c0 ^ 32;

  int nk = K >> 6;
  stage(0, 0);
  for (int t = 0; t < nk; ++t) {
    int b = t & 1;
    asm volatile("s_waitcnt vmcnt(0)" ::: "memory");
    __builtin_amdgcn_sched_barrier(0);
    __builtin_amdgcn_s_barrier();
    __builtin_amdgcn_sched_barrier(0);
    if (t + 1 < nk) stage(b ^ 1, t + 1);
    __builtin_amdgcn_sched_barrier(0);

    bf16x8 af[AF][2], bfr[NH2][2];
#pragma unroll
    for (int mf = 0; mf < AF; ++mf) {
      af[mf][0] = *(const bf16x8*)&As[b][(mf * 16 + lm) * 64 + c0 + wr * (BM / 2) * 64];
      af[mf][1] = *(const bf16x8*)&As[b][(mf * 16 + lm) * 64 + c1 + wr * (BM / 2) * 64];
    }
#pragma unroll
    for (int nf = 0; nf < NH2; ++nf) {
      int brow = wc * (BN / 2) + nf * 16 + lm;
      bfr[nf][0] = *(const bf16x8*)&Bs[b][brow * 64 + c0];
      bfr[nf][1] = *(const bf16x8*)&Bs[b][brow * 64 + c1];
    }
    __builtin_amdgcn_s_setprio(1);
#pragma unroll
    for (int mf = 0; mf < AF; ++mf)
#pragma unroll
      for (int nf = 0; nf < NH2; ++nf) {
        acc[mf][nf] = __builtin_amdgcn_mfma_f32_16x16x32_bf16(af[mf][0], bfr[nf][0], acc[mf][nf], 0, 0, 0);
        acc[mf][nf] = __builtin_amdgcn_mfma_f32_16x16x32_bf16(af[mf][1], bfr[nf][1], acc[mf][nf], 0, 0, 0);
      }
    __builtin_amdgcn_s_setprio(0);

#pragma unroll
    for (int nf = 0; nf < NH2; ++nf) {
      int brow = wc * (BN / 2) + (nf + NH2) * 16 + lm;
      bfr[nf][0] = *(const bf16x8*)&Bs[b][brow * 64 + c0];
      bfr[nf][1] = *(const bf16x8*)&Bs[b][brow * 64 + c1];
    }
    __builtin_amdgcn_s_setprio(1);
#pragma unroll
    for (int mf = 0; mf < AF; ++mf)
#pragma unroll
      for (int nf = 0; nf < NH2; ++nf) {
        acc[mf][nf + NH2] = __builtin_amdgcn_mfma_f32_16x16x32_bf16(af[mf][0], bfr[nf][0], acc[mf][nf + NH2], 0, 0, 0);
        acc[mf][nf + NH2] = __builtin_amdgcn_mfma_f32_16x16x32_bf16(af[mf][1], bfr[nf][1], acc[mf][nf + NH2], 0, 0, 0);
      }
    __builtin_amdgcn_s_setprio(0);
  }

#pragma unroll
  for (int mf = 0; mf < AF; ++mf)
#pragma unroll
    for (int nf = 0; nf < NFW; ++nf)
#pragma unroll
      for (int j = 0; j < 4; ++j) {
        int row = m0 + wr * (BM / 2) + mf * 16 + l4 * 4 + j;
        int col = n0 + wc * (BN / 2) + nf * 16 + lm;
        float v = acc[mf][nf][j];
        if constexpr (EPI == 0) {
          outb[(size_t)row * N + col] = f2b(v);
        } else if constexpr (EPI == 2) {
          v += bias[col];
          outb[(size_t)row * N + col] = f2b(fmaxf(v, 0.f));
        } else {
          v += bias[col];
          size_t o = (size_t)row * N + col;
          float nx = outf[o] + v;
          outf[o] = nx;
          outb[o] = f2b(nx);
        }
      }
}

// ---------------------------------------------------------------- attn + trans backfill
// blocks 0..255: attn(l), ONE q-tile per block (qb=bid&7) — spreads attention over
// all 256 CUs; causal imbalance (1..8 KV steps) absorbed by trans backfill blocks.
// Max-free softmax; ONE rsum16 after the KV loop; T14 async-stage.
// blocks 256..256+nTrans: next-layer weight transposes; rest: Wf chunk.
__global__ void __launch_bounds__(512, 2) k_attn_mega(
    const u16* __restrict__ qkv, u16* __restrict__ ob,
    const float* __restrict__ Wq, const float* __restrict__ Wk,
    const float* __restrict__ Wv, const float* __restrict__ Wo,
    const float* __restrict__ W1, const float* __restrict__ W2,
    const float* __restrict__ Wf, u16* __restrict__ wTnext,
    u16* __restrict__ wfT, int lNext, int wfStart) {
  __shared__ char smem[70656];
  int bid = blockIdx.x;
  if (bid >= 256) {
    auto t = reinterpret_cast<float(*)[65]>(smem);
    int i = bid - 256;
    int nTrans = (lNext < NL) ? 3072 : 0;
    if (i < nTrans) {
      trans512_blk(i, lNext, Wq, Wk, Wv, Wo, W1, W2,
                   wTnext, wTnext + (size_t)3 * ND * ND, wTnext + (size_t)4 * ND * ND,
                   wTnext + (size_t)8 * ND * ND, t);
    } else {
      int j = wfStart + (i - nTrans);  // Wf tile index [0, 8000)
      int x = j % 500, y = j / 500;
      tr512(Wf, NV, wfT, ND, y * 64, x * 64, t);
    }
    return;
  }
  // ---------------- attn: one q-tile ----------------
  u16* Ks = (u16*)smem;          // [128][72]
  u16* Vt = Ks + 128 * 72;       // [64][136]
  u16* Pw = Vt + 64 * 136;       // [8][16][136]
  int qb = bid & 7, h = (bid >> 3) & 15, b = bid >> 7;
  int tid = threadIdx.x;
  int w = tid >> 6, l = tid & 63;
  int l4 = l >> 4, lm = l & 15;

  const u16* base = qkv + (size_t)b * NT * 3072 + h * HDIM;
  int r0 = tid >> 3, e0 = (tid & 7) << 3;

  auto loadT = [&](int kb, bf16x8& k0, bf16x8& k1, bf16x8& v0, bf16x8& v1) {
    const u16* s0 = base + (size_t)(kb * 128 + r0) * 3072;
    const u16* s1 = s0 + (size_t)64 * 3072;
    k0 = *(const bf16x8*)(s0 + 1024 + e0);
    v0 = *(const bf16x8*)(s0 + 2048 + e0);
    k1 = *(const bf16x8*)(s1 + 1024 + e0);
    v1 = *(const bf16x8*)(s1 + 2048 + e0);
  };

  f32x4 z = {0.f, 0.f, 0.f, 0.f};

  bf16x8 qf[2];
#pragma unroll
  for (int kk = 0; kk < 2; ++kk) {
    int tq = qb * 128 + w * 16 + lm;
    qf[kk] = *(const bf16x8*)(base + (size_t)tq * 3072 + kk * 32 + l4 * 8);
  }

  f32x4 oacc[4];
  float lrow[4];
#pragma unroll
  for (int n = 0; n < 4; ++n) oacc[n] = z;
#pragma unroll
  for (int j = 0; j < 4; ++j) lrow[j] = 0.f;

  bf16x8 ck0, ck1, cv0, cv1;
  loadT(0, ck0, ck1, cv0, cv1);
  bf16x8 nk0 = ck0, nk1 = ck1, nv0 = cv0, nv1 = cv1;

  for (int kb = 0; kb <= qb; ++kb) {
    __syncthreads();
    {
      *(bf16x8*)&Ks[r0 * 72 + e0] = ck0;
      *(bf16x8*)&Ks[(r0 + 64) * 72 + e0] = ck1;
      union { bf16x8 v; u16 u[8]; } a, c;
      a.v = cv0; c.v = cv1;
#pragma unroll
      for (int j = 0; j < 8; ++j) {
        Vt[(e0 + j) * 136 + r0] = a.u[j];
        Vt[(e0 + j) * 136 + r0 + 64] = c.u[j];
      }
    }
    if (kb < qb) loadT(kb + 1, nk0, nk1, nv0, nv1);
    __syncthreads();

    f32x4 s[8];
#pragma unroll
    for (int n = 0; n < 8; ++n) s[n] = z;
#pragma unroll
    for (int kk = 0; kk < 2; ++kk)
#pragma unroll
      for (int n = 0; n < 8; ++n) {
        bf16x8 kf = *(const bf16x8*)&Ks[(n * 16 + lm) * 72 + kk * 32 + l4 * 8];
        s[n] = __builtin_amdgcn_mfma_f32_16x16x32_bf16(qf[kk], kf, s[n], 0, 0, 0);
      }

    bool diag = (kb == qb);
#pragma unroll
    for (int j = 0; j < 4; ++j) {
      int rloc = w * 16 + l4 * 4 + j;
      int prow = l4 * 4 + j;
      float rs = 0.f;
#pragma unroll
      for (int n = 0; n < 8; ++n) {
        float p = exp2f(s[n][j] * (0.03125f * L2E));
        if (diag && (n * 16 + lm > rloc)) p = 0.f;
        rs += p;
        Pw[(w * 16 + prow) * 136 + n * 16 + lm] = f2b(p);
      }
      lrow[j] += rs;
    }
    asm volatile("s_waitcnt lgkmcnt(0)" ::: "memory");
    __builtin_amdgcn_sched_barrier(0);

#pragma unroll
    for (int kk = 0; kk < 4; ++kk) {
      bf16x8 pa = *(const bf16x8*)&Pw[(w * 16 + lm) * 136 + kk * 32 + l4 * 8];
#pragma unroll
      for (int n = 0; n < 4; ++n) {
        bf16x8 vf = *(const bf16x8*)&Vt[(n * 16 + lm) * 136 + kk * 32 + l4 * 8];
        oacc[n] = __builtin_amdgcn_mfma_f32_16x16x32_bf16(pa, vf, oacc[n], 0, 0, 0);
      }
    }

    ck0 = nk0; ck1 = nk1; cv0 = nv0; cv1 = nv1;
  }

#pragma unroll
  for (int j = 0; j < 4; ++j) lrow[j] = rsum16(lrow[j]);

#pragma unroll
  for (int n = 0; n < 4; ++n)
#pragma unroll
    for (int j = 0; j < 4; ++j) {
      int tq = qb * 128 + w * 16 + l4 * 4 + j;
      int col = h * HDIM + n * 16 + lm;
      float v = oacc[n][j] / lrow[j];
      ob[(size_t)(b * NT + tq) * ND + col] = f2b(v);
    }
}

// ---------------------------------------------------------------- layernorm
__global__ void k_ln(const float* __restrict__ xf, const float* __restrict__ g,
                     const float* __restrict__ bta, u16* __restrict__ xb) {
  __shared__ float red[4];
  int row = blockIdx.x, tid = threadIdx.x;
  int w = tid >> 6;
  int c = tid * 4;
  float4 x = *(const float4*)(xf + (size_t)row * ND + c);
  float s = x.x + x.y + x.z + x.w;
#pragma unroll
  for (int off = 1; off < 64; off <<= 1) s += __shfl_xor(s, off, 64);
  if ((tid & 63) == 0) red[w] = s;
  __syncthreads();
  float mu = (red[0] + red[1] + red[2] + red[3]) * (1.0f / ND);
  float d0 = x.x - mu, d1 = x.y - mu, d2 = x.z - mu, d3 = x.w - mu;
  float v = d0 * d0 + d1 * d1 + d2 * d2 + d3 * d3;
  __syncthreads();
#pragma unroll
  for (int off = 1; off < 64; off <<= 1) v += __shfl_xor(v, off, 64);
  if ((tid & 63) == 0) red[w] = v;
  __syncthreads();
  float var = (red[0] + red[1] + red[2] + red[3]) * (1.0f / ND);
  float rs = rsqrtf(var + 1e-5f);
  float4 gg = *(const float4*)(g + c);
  float4 bb = *(const float4*)(bta + c);
  u16* o = xb + (size_t)row * ND + c;
  o[0] = f2b(d0 * rs * gg.x + bb.x);
  o[1] = f2b(d1 * rs * gg.y + bb.y);
  o[2] = f2b(d2 * rs * gg.z + bb.z);
  o[3] = f2b(d3 * rs * gg.w + bb.w);
}

// ---------------------------------------------------------------- loss (from partials)
__global__ void k_loss_row2(const float* __restrict__ pl, const float* __restrict__ logits,
                            const int* __restrict__ tgt, float* __restrict__ lossbuf) {
  int row = blockIdx.x, l = threadIdx.x;  // 64 threads
  const float* pr = pl + (size_t)row * NSLOT;
  float s = 0.f;
  for (int i = l; i < NSLOT; i += 64) s += pr[i];
#pragma unroll
  for (int off = 1; off < 64; off <<= 1) s += __shfl_xor(s, off, 64);
  if (l == 0) lossbuf[row] = logf(s) - logits[(size_t)row * NV + tgt[row]];
}

__global__ void k_loss_final(const float* __restrict__ lossbuf, float* __restrict__ out) {
  __shared__ float red[4];
  int tid = threadIdx.x;
  float s = 0.f;
  for (int i = tid; i < BT; i += 256) s += lossbuf[i];
#pragma unroll
  for (int off = 1; off < 64; off <<= 1) s += __shfl_xor(s, off, 64);
  if ((tid & 63) == 0) red[tid >> 6] = s;
  __syncthreads();
  if (tid == 0) out[0] = (red[0] + red[1] + red[2] + red[3]) * (1.0f / BT);
}

// ---------------------------------------------------------------- launch
extern "C" void kernel_launch(void* const* d_in, const int* in_sizes, int n_in,
                              void* d_out, int out_size, void* d_ws, size_t ws_size,
                              hipStream_t stream) {
  const int* idx = (const int*)d_in[0];
  const int* tgt = (const int*)d_in[1];
  const float* tok = (const float*)d_in[2];
  const float* pos = (const float*)d_in[3];
  const float* Wq = (const float*)d_in[4];
  const float* Wk = (const float*)d_in[5];
  const float* Wv = (const float*)d_in[6];
  const float* Wo = (const float*)d_in[7];
  const float* bo = (const float*)d_in[8];
  const float* W1 = (const float*)d_in[9];
  const float* b1 = (const float*)d_in[10];
  const float* W2 = (const float*)d_in[11];
  const float* b2 = (const float*)d_in[12];
  const float* lng = (const float*)d_in[13];
  const float* lnb = (const float*)d_in[14];
  const float* Wf = (const float*)d_in[15];
  const float* bfp = (const float*)d_in[16];
  float* logits = (float*)d_out;
  float* lossp = logits + (size_t)BT * NV;

  char* ws = (char*)d_ws;
  u16* wT0 = (u16*)ws;                                   // 12*D^2 u16 = 25.2 MB
  u16* wT1 = wT0 + (size_t)12 * ND * ND;                 // 25.2 MB
  u16* wfT = wT1 + (size_t)12 * ND * ND;                 // 65.5 MB
  size_t off = (size_t)24 * ND * ND * 2 + (size_t)NV * ND * 2;
  float* xf = (float*)(ws + off); off += (size_t)BT * ND * 4;
  u16* xb = (u16*)(ws + off);     off += (size_t)BT * ND * 2;
  u16* qkv = (u16*)(ws + off);    off += (size_t)BT * 3 * ND * 2;
  u16* obuf = (u16*)(ws + off);   off += (size_t)BT * ND * 2;
  u16* hb = (u16*)(ws + off);     off += (size_t)BT * ND4 * 2;
  float* pl = (float*)(ws + off); off += (size_t)BT * NSLOT * 4;
  float* lossbuf = (float*)(ws + off);

  k_pre<<<4096, 512, 0, stream>>>(idx, tok, pos, xf, xb, Wq, Wk, Wv, Wo, W1, W2, wT0);
  int wfDone = 0;
  for (int l = 0; l < NL; ++l) {
    u16* wTl = (l & 1) ? wT1 : wT0;
    u16* wTn = (l & 1) ? wT0 : wT1;
    u16* wqkvT = wTl;
    u16* woT = wTl + (size_t)3 * ND * ND;
    u16* w1T = wTl + (size_t)4 * ND * ND;
    u16* w2T = wTl + (size_t)8 * ND * ND;
    k_gemm4<0, 128, 128><<<384, 256, 0, stream>>>(xb, wqkvT, nullptr, nullptr, qkv, ND, 3 * ND, 16);
    int nTrans = (l + 1 < NL) ? 3072 : 0;
    int wfCount = (l + 1 < NL) ? 1333 : (8000 - wfDone);
    k_attn_mega<<<256 + nTrans + wfCount, 512, 0, stream>>>(
        qkv, obuf, Wq, Wk, Wv, Wo, W1, W2, Wf, wTn, wfT, l + 1, wfDone);
    wfDone += wfCount;
    k_gemm4<3, 64, 64><<<512, 256, 0, stream>>>(obuf, woT, bo + (size_t)l * ND, xf, xb, ND, ND, 32);
    k_gemm4<2, 128, 128><<<512, 256, 0, stream>>>(xb, w1T, b1 + (size_t)l * ND4, nullptr, hb, ND, ND4, 16);
    k_gemm4<3, 64, 64><<<512, 256, 0, stream>>>(hb, w2T, b2 + (size_t)l * ND, xf, xb, ND4, ND, 32);
  }
  k_ln<<<BT, 256, 0, stream>>>(xf, lng, lnb, xb);
  k_gemm8<4><<<1000, 512, 0, stream>>>(xb, wfT, bfp, logits, nullptr, ND, NV, 8, pl);
  k_loss_row2<<<BT, 64, 0, stream>>>(pl, logits, tgt, lossbuf);
  k_loss_final<<<1, 256, 0, stream>>>(lossbuf, lossp);
}